// Round 8
// baseline (265.328 us; speedup 1.0000x reference)
//
#include <hip/hip_runtime.h>
#include <cstdint>

#define HDIM 256
#define MT   128      // feature rows per block (4 waves x 32 rows)
#define BD   32       // En rows per K-loop iteration
#define SPLITS 32

typedef short bf16x8 __attribute__((ext_vector_type(8)));
typedef float f32x4  __attribute__((ext_vector_type(4)));

static __device__ __forceinline__ short f2bf(float x) {
    union { float f; uint32_t u; } v; v.f = x;
    uint32_t u = v.u;
    uint32_t r = (u + 0x7fffu + ((u >> 16) & 1u)) >> 16;
    return (short)r;
}

// ---- prep (single dispatch):
//  blocks [0, nb_nrm)          : L2-normalize feature/ex_feature rows -> bf16
//                                (plain row-major; no swizzle — B path is LDS-free)
//  blocks [nb_nrm, nb_nrm+128) : transpose class reps to Rt[32][D] (col C = 1.0
//                                -> intensity falls out of the echo GEMM)
__global__ __launch_bounds__(256) void prep_kernel(const float* __restrict__ fsrc,
                                                   const float* __restrict__ esrc,
                                                   const float* __restrict__ reps,
                                                   short* __restrict__ dst,
                                                   short* __restrict__ rt,
                                                   int N, int rows_total,
                                                   int D, int C, int nb_nrm) {
    __shared__ float lds[128][29];                    // +1 pad col
    const int tid = threadIdx.x;
    if ((int)blockIdx.x < nb_nrm) {
        int wv = tid >> 6;
        int lane = tid & 63;
        int row = blockIdx.x * 4 + wv;
        if (row >= rows_total) return;
        const float* src = (row < N) ? (fsrc + (size_t)row * HDIM)
                                     : (esrc + (size_t)(row - N) * HDIM);
        const float4 v = *(const float4*)(src + lane * 4);
        float ss = v.x * v.x + v.y * v.y + v.z * v.z + v.w * v.w;
        #pragma unroll
        for (int m = 1; m < 64; m <<= 1) ss += __shfl_xor(ss, m, 64);
        float scale = 1.0f / fmaxf(sqrtf(ss), 1e-12f);
        short4 o;
        o.x = f2bf(v.x * scale); o.y = f2bf(v.y * scale);
        o.z = f2bf(v.z * scale); o.w = f2bf(v.w * scale);
        *(short4*)(dst + (size_t)row * HDIM + lane * 4) = o;
    } else {
        const int bx = blockIdx.x - nb_nrm;           // 0..127
        const int d0 = bx * 128;
        const int total = 128 * C;
        const float* src = reps + (size_t)d0 * C;
        for (int i = tid; i < total; i += 256)
            lds[i / C][i % C] = src[i];               // coalesced load
        __syncthreads();
        const int c = tid >> 3;                       // 0..31
        const int dsub = (tid & 7) * 16;              // 16 d per thread
        short* dstp = rt + (size_t)c * D + d0 + dsub;
        #pragma unroll
        for (int j0 = 0; j0 < 16; j0 += 4) {
            short4 o;
            float v0, v1, v2, v3;
            if (c < C) {
                v0 = lds[dsub + j0 + 0][c]; v1 = lds[dsub + j0 + 1][c];
                v2 = lds[dsub + j0 + 2][c]; v3 = lds[dsub + j0 + 3][c];
            } else {
                float f = (c == C) ? 1.0f : 0.0f;     // ones column -> intensity
                v0 = v1 = v2 = v3 = f;
            }
            o.x = f2bf(v0); o.y = f2bf(v1); o.z = f2bf(v2); o.w = f2bf(v3);
            *(short4*)(dstp + j0) = o;                // coalesced store
        }
    }
}

// ---- fused, barrier-free: B fragments come straight from global (L2-resident
// En; grid.x=split keeps each split's En chunk on one XCD's L2). No staging,
// no double buffer, no __syncthreads — waves free-run with per-iter MLP.
// LDS only holds the tiny C->A-layout bounce buffer for GEMM2. ----
__global__ __launch_bounds__(256, 3) void fused_kernel(const short* __restrict__ Fn,
                                                       const short* __restrict__ En,
                                                       const short* __restrict__ Rt,
                                                       const int* __restrict__ pptr,
                                                       float* __restrict__ partial,
                                                       int N, int D, int C, int Dchunk) {
    __shared__ __align__(16) short abuf[4][2][16][40];     // 10 KB, stride 80B

    const int tid  = threadIdx.x;
    const int lane = tid & 63;
    const int wv   = tid >> 6;
    const int q    = lane >> 4;
    const int l    = lane & 15;
    const int p    = pptr[0];

    const int Mbase = blockIdx.y * MT;
    const int dbase = blockIdx.x * Dchunk;

    const f32x4 zf = {0.0f, 0.0f, 0.0f, 0.0f};

    // A fragments from global (plain layout): A[m=l][k=ks*32+q*8+j]
    bf16x8 afrag[2][8];
    #pragma unroll
    for (int mb = 0; mb < 2; ++mb) {
        const short* rowp = Fn + (size_t)(Mbase + wv * 32 + mb * 16 + l) * HDIM + q * 8;
        #pragma unroll
        for (int ks = 0; ks < 8; ++ks)
            afrag[mb][ks] = *(const bf16x8*)(rowp + ks * 32);
    }

    f32x4 echo_acc[2][2];
    echo_acc[0][0] = zf; echo_acc[0][1] = zf;
    echo_acc[1][0] = zf; echo_acc[1][1] = zf;

    // Per-lane B base pointers for the two 16-row groups (cb=0,1)
    const short* enb0 = En + (size_t)(dbase + l) * HDIM + q * 8;
    const short* enb1 = En + (size_t)(dbase + 16 + l) * HDIM + q * 8;
    const short* rt0  = Rt + (size_t)l * D + q * 8;
    const short* rt1  = Rt + (size_t)(16 + l) * D + q * 8;

    const int iters = Dchunk / BD;

    for (int it = 0; it < iters; ++it) {
        const size_t doff = (size_t)it * BD * HDIM;    // 32 rows per iter
        const int d0 = dbase + it * BD;

        // GEMM1: S tile 32(M) x 32(D) per wave, K=256.
        // 16 independent 1KB global loads; full unroll lets the compiler
        // hoist them and interleave MFMA <-> vmcnt waits.
        f32x4 s[2][2];
        s[0][0] = zf; s[0][1] = zf; s[1][0] = zf; s[1][1] = zf;
        #pragma unroll
        for (int ks = 0; ks < 8; ++ks) {
            bf16x8 bf0 = *(const bf16x8*)(enb0 + doff + ks * 32);
            bf16x8 bf1 = *(const bf16x8*)(enb1 + doff + ks * 32);
            s[0][0] = __builtin_amdgcn_mfma_f32_16x16x32_bf16(afrag[0][ks], bf0, s[0][0], 0, 0, 0);
            s[1][0] = __builtin_amdgcn_mfma_f32_16x16x32_bf16(afrag[1][ks], bf0, s[1][0], 0, 0, 0);
            s[0][1] = __builtin_amdgcn_mfma_f32_16x16x32_bf16(afrag[0][ks], bf1, s[0][1], 0, 0, 0);
            s[1][1] = __builtin_amdgcn_mfma_f32_16x16x32_bf16(afrag[1][ks], bf1, s[1][1], 0, 0, 0);
        }

        // activation for both mb -> abuf (same-wave LDS round-trip) -> GEMM2
        #pragma unroll
        for (int mb = 0; mb < 2; ++mb) {
            #pragma unroll
            for (int cb = 0; cb < 2; ++cb) {
                #pragma unroll
                for (int r = 0; r < 4; ++r) {
                    float sv = s[mb][cb][r];
                    float a;
                    if (p == 3)      a = sv * sv * sv;
                    else if (p == 1) a = sv;
                    else if (p == 2) a = sv * fabsf(sv);
                    else             a = copysignf(powf(fabsf(sv), (float)p), sv);
                    abuf[wv][mb][q * 4 + r][cb * 16 + l] = f2bf(a);
                }
            }
        }
        bf16x8 b20 = *(const bf16x8*)(rt0 + d0);
        bf16x8 b21 = *(const bf16x8*)(rt1 + d0);
        #pragma unroll
        for (int mb = 0; mb < 2; ++mb) {
            bf16x8 a2 = *(const bf16x8*)(&abuf[wv][mb][l][q * 8]);
            echo_acc[mb][0] = __builtin_amdgcn_mfma_f32_16x16x32_bf16(a2, b20, echo_acc[mb][0], 0, 0, 0);
            echo_acc[mb][1] = __builtin_amdgcn_mfma_f32_16x16x32_bf16(a2, b21, echo_acc[mb][1], 0, 0, 0);
        }
    }

    // Epilogue: plain stores to this split's partial region [N][32]
    // (col C holds intensity via the ones column in Rt)
    #pragma unroll
    for (int mb = 0; mb < 2; ++mb) {
        #pragma unroll
        for (int nb = 0; nb < 2; ++nb) {
            const int c = nb * 16 + l;
            if (c <= C) {
                #pragma unroll
                for (int r = 0; r < 4; ++r) {
                    const int grow = Mbase + wv * 32 + mb * 16 + q * 4 + r;
                    partial[((size_t)blockIdx.x * N + grow) * 32 + c] = echo_acc[mb][nb][r];
                }
            }
        }
    }
}

// ---- reduce: sum partials over splits; col<C -> echo, col==C -> intensity ----
__global__ __launch_bounds__(256) void reduce_kernel(const float* __restrict__ partial,
                                                     float* __restrict__ echo,
                                                     float* __restrict__ inten,
                                                     int N, int splits, int C) {
    int t = blockIdx.x * 256 + threadIdx.x;    // N*32 threads
    int row = t >> 5, c = t & 31;
    if (row >= N || c > C) return;
    float s = 0.0f;
    for (int k = 0; k < splits; ++k)
        s += partial[((size_t)k * N + (size_t)row) * 32 + c];
    if (c < C) echo[(size_t)row * C + c] = s;
    else       inten[row] = s;
}

extern "C" void kernel_launch(void* const* d_in, const int* in_sizes, int n_in,
                              void* d_out, int out_size, void* d_ws, size_t ws_size,
                              hipStream_t stream) {
    const int N = in_sizes[0] / HDIM;       // 4096
    const int D = in_sizes[1] / HDIM;       // 16384
    const int C = in_sizes[2] / D;          // 28

    const float* feat = (const float*)d_in[0];
    const float* exf  = (const float*)d_in[1];
    const float* reps = (const float*)d_in[2];
    const int*   p    = (const int*)d_in[3];

    short* Fn = (short*)d_ws;                          // [N][256] bf16
    short* En = Fn + (size_t)N * HDIM;                 // [D][256] bf16
    short* Rt = En + (size_t)D * HDIM;                 // [32][D] bf16 (col C = 1.0)
    float* partial = (float*)(Rt + (size_t)32 * D);    // [SPLITS][N][32] f32

    float* echo  = (float*)d_out;
    float* inten = echo + (size_t)N * C;

    const int nb_nrm = (N + D) / 4;
    hipLaunchKernelGGL(prep_kernel, dim3(nb_nrm + D / 128), dim3(256), 0, stream,
                       feat, exf, reps, Fn, Rt, N, N + D, D, C, nb_nrm);

    // grid.x = split: linearized block id % 8 == split % 8, so all row-tiles
    // of one split land on the same XCD -> its En chunk stays in that L2.
    const int Dchunk = D / SPLITS;
    hipLaunchKernelGGL(fused_kernel, dim3(SPLITS, N / MT), dim3(256), 0, stream,
                       Fn, En, Rt, p, partial, N, D, C, Dchunk);

    hipLaunchKernelGGL(reduce_kernel, dim3(N * 32 / 256), dim3(256), 0, stream,
                       partial, echo, inten, N, SPLITS, C);
}

// Round 9
// 143.537 us; speedup vs baseline: 1.8485x; 1.8485x over previous
//
#include <hip/hip_runtime.h>
#include <cstdint>

#define HDIM 256
#define MT   128      // feature rows per block (4 waves x 32 rows)
#define BD   32       // En rows per K-loop iteration
#define SPLITS 32

typedef short bf16x8 __attribute__((ext_vector_type(8)));
typedef short bf16x4 __attribute__((ext_vector_type(4)));
typedef float f32x4  __attribute__((ext_vector_type(4)));

typedef const __attribute__((address_space(1))) short as1_short;
typedef __attribute__((address_space(3))) short as3_short;

static __device__ __forceinline__ short f2bf(float x) {
    union { float f; uint32_t u; } v; v.f = x;
    uint32_t u = v.u;
    uint32_t r = (u + 0x7fffu + ((u >> 16) & 1u)) >> 16;
    return (short)r;
}

// ---- prep (single dispatch):
//  blocks [0, nb_nrm)          : L2-normalize feature/ex_feature rows -> bf16,
//                                stored with XOR-16B-chunk swizzle
//  blocks [nb_nrm, nb_nrm+128) : transpose class reps to Rt[32][D] (col C = 1.0
//                                -> intensity falls out of the echo GEMM)
__global__ __launch_bounds__(256) void prep_kernel(const float* __restrict__ fsrc,
                                                   const float* __restrict__ esrc,
                                                   const float* __restrict__ reps,
                                                   short* __restrict__ dst,
                                                   short* __restrict__ rt,
                                                   int N, int rows_total,
                                                   int D, int C, int nb_nrm) {
    __shared__ float lds[128][29];                    // +1 pad col
    const int tid = threadIdx.x;
    if ((int)blockIdx.x < nb_nrm) {
        int wv = tid >> 6;
        int lane = tid & 63;
        int row = blockIdx.x * 4 + wv;
        if (row >= rows_total) return;
        const float* src = (row < N) ? (fsrc + (size_t)row * HDIM)
                                     : (esrc + (size_t)(row - N) * HDIM);
        const float4 v = *(const float4*)(src + lane * 4);
        float ss = v.x * v.x + v.y * v.y + v.z * v.z + v.w * v.w;
        #pragma unroll
        for (int m = 1; m < 64; m <<= 1) ss += __shfl_xor(ss, m, 64);
        float scale = 1.0f / fmaxf(sqrtf(ss), 1e-12f);
        short4 o;
        o.x = f2bf(v.x * scale); o.y = f2bf(v.y * scale);
        o.z = f2bf(v.z * scale); o.w = f2bf(v.w * scale);
        int chunk = (lane >> 1) ^ (row & 7);          // swizzled 16B-chunk index
        *(short4*)(dst + (size_t)row * HDIM + chunk * 8 + (lane & 1) * 4) = o;
    } else {
        const int bx = blockIdx.x - nb_nrm;           // 0..127
        const int d0 = bx * 128;
        const int total = 128 * C;
        const float* src = reps + (size_t)d0 * C;
        for (int i = tid; i < total; i += 256)
            lds[i / C][i % C] = src[i];               // coalesced load
        __syncthreads();
        const int c = tid >> 3;                       // 0..31
        const int dsub = (tid & 7) * 16;              // 16 d per thread
        short* dstp = rt + (size_t)c * D + d0 + dsub;
        #pragma unroll
        for (int j0 = 0; j0 < 16; j0 += 4) {
            short4 o;
            float v0, v1, v2, v3;
            if (c < C) {
                v0 = lds[dsub + j0 + 0][c]; v1 = lds[dsub + j0 + 1][c];
                v2 = lds[dsub + j0 + 2][c]; v3 = lds[dsub + j0 + 3][c];
            } else {
                float f = (c == C) ? 1.0f : 0.0f;     // ones column -> intensity
                v0 = v1 = v2 = v3 = f;
            }
            o.x = f2bf(v0); o.y = f2bf(v1); o.z = f2bf(v2); o.w = f2bf(v3);
            *(short4*)(dstp + j0) = o;                // coalesced store
        }
    }
}

// ---- fused: GEMM1 computes S^T via operand-swapped MFMA (A=En, B=Fn), so the
// activated tile sits in 16x16x16 B-operand layout (C/D layout == B layout for
// K=16 MFMA) and feeds GEMM2 echo^T += Rt_frag * a^T with NO LDS round-trip.
// En staged via global_load_lds double buffer (r8 proved direct-global B dies
// on scattered TA segments). XOR de-swizzle stays in per-lane addresses (r5). ----
__global__ __launch_bounds__(256, 4) void fused_kernel(const short* __restrict__ Fn,
                                                       const short* __restrict__ En,
                                                       const short* __restrict__ Rt,
                                                       const int* __restrict__ pptr,
                                                       float* __restrict__ partial,
                                                       int N, int D, int C, int Dchunk) {
    __shared__ __align__(16) short lds_en[2][BD * HDIM];   // 2 x 16 KB double buffer

    const int tid  = threadIdx.x;
    const int lane = tid & 63;
    const int wv   = tid >> 6;
    const int q    = lane >> 4;
    const int l    = lane & 15;
    const int p    = pptr[0];

    const int Mbase = blockIdx.y * MT;
    const int dbase = blockIdx.x * Dchunk;

    const f32x4 zf = {0.0f, 0.0f, 0.0f, 0.0f};

    // Fn fragments (B-operand of GEMM1): B[k=ks*32+q*8+j][n=l] — per-lane data
    // identical to the old A-frag; de-swizzle in the address.
    bf16x8 afrag[2][8];
    #pragma unroll
    for (int fn = 0; fn < 2; ++fn) {
        const short* rowp = Fn + (size_t)(Mbase + wv * 32 + fn * 16 + l) * HDIM;
        #pragma unroll
        for (int ks = 0; ks < 8; ++ks)
            afrag[fn][ks] = *(const bf16x8*)(rowp + (((ks * 4 + q) ^ (l & 7)) << 3));
    }

    // echo^T accumulators: [f-tile][c-tile], C/D layout col=f(l), row=c(q*4+r)
    f32x4 echo_acc[2][2];
    echo_acc[0][0] = zf; echo_acc[0][1] = zf;
    echo_acc[1][0] = zf; echo_acc[1][1] = zf;

    const int iters = Dchunk / BD;

    #define STAGE(buf_, it_)                                                        \
        {                                                                           \
            const short* gbase = En + (size_t)(dbase + (it_) * BD) * HDIM + tid * 8;\
            _Pragma("unroll")                                                       \
            for (int i = 0; i < 4; ++i) {                                           \
                as3_short* lp = (as3_short*)(lds_en[buf_] + (i * 256 + wv * 64) * 8);\
                __builtin_amdgcn_global_load_lds((as1_short*)(gbase + i * 2048),    \
                                                 lp, 16, 0, 0);                     \
            }                                                                       \
        }

    STAGE(0, 0)

    const short* rtp = Rt + (size_t)l * D + q * 4;    // c-tile 0 row; +16*D for tile 1

    for (int it = 0; it < iters; ++it) {
        const int buf = it & 1;
        __syncthreads();                 // stage(it) landed; all waves done with buf^1
        if (it + 1 < iters) STAGE(buf ^ 1, it + 1)

        const int d0 = dbase + it * BD;

        // GEMM1: S^T tiles [en=d-block][fn=f-tile], 32(D) x 32(M) per wave, K=256
        f32x4 sT[2][2];
        sT[0][0] = zf; sT[0][1] = zf; sT[1][0] = zf; sT[1][1] = zf;
        #pragma unroll
        for (int ks = 0; ks < 8; ++ks) {
            #pragma unroll
            for (int en = 0; en < 2; ++en) {
                const int row  = en * 16 + l;
                const int slot = (ks * 4 + q) ^ (l & 7);
                bf16x8 ef = *(const bf16x8*)(lds_en[buf] + row * HDIM + slot * 8);
                sT[en][0] = __builtin_amdgcn_mfma_f32_16x16x32_bf16(ef, afrag[0][ks], sT[en][0], 0, 0, 0);
                sT[en][1] = __builtin_amdgcn_mfma_f32_16x16x32_bf16(ef, afrag[1][ks], sT[en][1], 0, 0, 0);
            }
        }

        // activation in-register -> packed bf16x4 (already 16x16x16 B-layout)
        bf16x4 pfrag[2][2];              // [f-tile][d-block]
        #pragma unroll
        for (int en = 0; en < 2; ++en) {
            #pragma unroll
            for (int fn = 0; fn < 2; ++fn) {
                bf16x4 pf;
                #pragma unroll
                for (int r = 0; r < 4; ++r) {
                    float sv = sT[en][fn][r];
                    float a;
                    if (p == 3)      a = sv * sv * sv;
                    else if (p == 1) a = sv;
                    else if (p == 2) a = sv * fabsf(sv);
                    else             a = copysignf(powf(fabsf(sv), (float)p), sv);
                    pf[r] = f2bf(a);
                }
                pfrag[fn][en] = pf;
            }
        }

        // GEMM2: echo^T += Rt_frag(A) * a^T(B), 16x16x16, K=32 via 2 d-blocks
        #pragma unroll
        for (int dblk = 0; dblk < 2; ++dblk) {
            const int doff = d0 + dblk * 16;
            bf16x4 rt0 = *(const bf16x4*)(rtp + doff);              // c-tile 0
            bf16x4 rt1 = *(const bf16x4*)(rtp + (size_t)16 * D + doff); // c-tile 1
            #pragma unroll
            for (int fn = 0; fn < 2; ++fn) {
                echo_acc[fn][0] = __builtin_amdgcn_mfma_f32_16x16x16bf16_1k(rt0, pfrag[fn][dblk], echo_acc[fn][0], 0, 0, 0);
                echo_acc[fn][1] = __builtin_amdgcn_mfma_f32_16x16x16bf16_1k(rt1, pfrag[fn][dblk], echo_acc[fn][1], 0, 0, 0);
            }
        }
    }

    // Epilogue: echo^T C-layout (col f = l, rows c = ct*16 + q*4 + r) -> one
    // float4 store per (f-tile, c-tile); reduce kernel ignores c > C.
    #pragma unroll
    for (int fn = 0; fn < 2; ++fn) {
        const int grow = Mbase + wv * 32 + fn * 16 + l;
        float* rowp = partial + ((size_t)blockIdx.x * N + grow) * 32 + q * 4;
        *(f32x4*)(rowp)      = echo_acc[fn][0];
        *(f32x4*)(rowp + 16) = echo_acc[fn][1];
    }
}

// ---- reduce: sum partials over splits; col<C -> echo, col==C -> intensity ----
__global__ __launch_bounds__(256) void reduce_kernel(const float* __restrict__ partial,
                                                     float* __restrict__ echo,
                                                     float* __restrict__ inten,
                                                     int N, int splits, int C) {
    int t = blockIdx.x * 256 + threadIdx.x;    // N*32 threads
    int row = t >> 5, c = t & 31;
    if (row >= N || c > C) return;
    float s = 0.0f;
    for (int k = 0; k < splits; ++k)
        s += partial[((size_t)k * N + (size_t)row) * 32 + c];
    if (c < C) echo[(size_t)row * C + c] = s;
    else       inten[row] = s;
}

extern "C" void kernel_launch(void* const* d_in, const int* in_sizes, int n_in,
                              void* d_out, int out_size, void* d_ws, size_t ws_size,
                              hipStream_t stream) {
    const int N = in_sizes[0] / HDIM;       // 4096
    const int D = in_sizes[1] / HDIM;       // 16384
    const int C = in_sizes[2] / D;          // 28

    const float* feat = (const float*)d_in[0];
    const float* exf  = (const float*)d_in[1];
    const float* reps = (const float*)d_in[2];
    const int*   p    = (const int*)d_in[3];

    short* Fn = (short*)d_ws;                          // [N][256] bf16 (swizzled)
    short* En = Fn + (size_t)N * HDIM;                 // [D][256] bf16 (swizzled)
    short* Rt = En + (size_t)D * HDIM;                 // [32][D] bf16 (col C = 1.0)
    float* partial = (float*)(Rt + (size_t)32 * D);    // [SPLITS][N][32] f32

    float* echo  = (float*)d_out;
    float* inten = echo + (size_t)N * C;

    const int nb_nrm = (N + D) / 4;
    hipLaunchKernelGGL(prep_kernel, dim3(nb_nrm + D / 128), dim3(256), 0, stream,
                       feat, exf, reps, Fn, Rt, N, N + D, D, C, nb_nrm);

    const int Dchunk = D / SPLITS;
    hipLaunchKernelGGL(fused_kernel, dim3(SPLITS, N / MT), dim3(256), 0, stream,
                       Fn, En, Rt, p, partial, N, D, C, Dchunk);

    hipLaunchKernelGGL(reduce_kernel, dim3(N * 32 / 256), dim3(256), 0, stream,
                       partial, echo, inten, N, SPLITS, C);
}